// Round 1
// baseline (18.021 us; speedup 1.0000x reference)
//
#include <hip/hip_runtime.h>

#define B_ 8
#define C_ 64
#define N_ 4096
#define K_ 16

// Kernel 1: x[B,C,N] -> xt[B,N,C], 64x64 tiles via LDS (pad 65 -> conflict-free).
__global__ __launch_bounds__(256) void transpose_k(const float* __restrict__ x,
                                                   float* __restrict__ xt) {
  __shared__ float tile[64][65];
  const int bid = blockIdx.x;          // B * (N/64) = 512 blocks
  const int b   = bid & 7;             // batch on low bits: per-XCD batch locality
  const int n0  = (bid >> 3) * 64;
  const int t   = threadIdx.x;
  const int m   = t & 15;              // float4 lane within row
  const int g   = t >> 4;              // row group
#pragma unroll
  for (int it = 0; it < 4; ++it) {
    const int c = it * 16 + g;
    const float4 v = *reinterpret_cast<const float4*>(
        &x[((size_t)b * C_ + c) * N_ + n0 + m * 4]);
    tile[c][m * 4 + 0] = v.x; tile[c][m * 4 + 1] = v.y;
    tile[c][m * 4 + 2] = v.z; tile[c][m * 4 + 3] = v.w;
  }
  __syncthreads();
#pragma unroll
  for (int it = 0; it < 4; ++it) {
    const int j = it * 16 + g;
    float4 v;
    v.x = tile[m * 4 + 0][j]; v.y = tile[m * 4 + 1][j];
    v.z = tile[m * 4 + 2][j]; v.w = tile[m * 4 + 3][j];
    *reinterpret_cast<float4*>(&xt[((size_t)b * N_ + n0 + j) * C_ + m * 4]) = v;
  }
}

// Kernel 2: per (b, 64-node tile): gather-sum neighbor rows from xt (contiguous
// 256B per edge), accumulate 64x64 tile in LDS, transposed coalesced write-out
// fused with (1+alpha)*x.
__global__ __launch_bounds__(256) void aggregate_k(const float* __restrict__ x,
                                                   const float* __restrict__ xt,
                                                   const int* __restrict__ ei,
                                                   const float* __restrict__ alpha_p,
                                                   float* __restrict__ out) {
  __shared__ int   idxs[64 * K_];      // 4 KB
  __shared__ float msum[64 * 65];      // 16.6 KB, stride 65 (65 mod 32 = 1)
  const int bid = blockIdx.x;          // 512 blocks
  const int b   = bid & 7;
  const int n0  = (bid >> 3) * 64;
  const int t   = threadIdx.x;

  // stage edge indices for the 64 nodes: 1024 ints as 256 int4 (coalesced)
  reinterpret_cast<int4*>(idxs)[t] =
      reinterpret_cast<const int4*>(&ei[((size_t)b * N_ + n0) * K_])[t];
  __syncthreads();

  const float s = 1.0f + alpha_p[0];
  const int m = t & 15;                // float4 channel group (channels 4m..4m+3)
  const int g = t >> 4;                // node sub-group
  const float* xtb = xt + (size_t)b * N_ * C_;

#pragma unroll
  for (int it = 0; it < 4; ++it) {
    const int j = it * 16 + g;         // local node
    const int* mi = &idxs[j * K_];     // same addr across the 16 lanes -> broadcast
    float4 acc = make_float4(0.f, 0.f, 0.f, 0.f);
#pragma unroll
    for (int k = 0; k < K_; ++k) {
      const float4 v = *reinterpret_cast<const float4*>(
          &xtb[(size_t)mi[k] * C_ + m * 4]);
      acc.x += v.x; acc.y += v.y; acc.z += v.z; acc.w += v.w;
    }
    float* mp = &msum[j * 65 + m * 4];
    mp[0] = acc.x; mp[1] = acc.y; mp[2] = acc.z; mp[3] = acc.w;
  }
  __syncthreads();

  // write-out: lanes over nodes (coalesced 256B rows), fused self-term
  const int j  = t & 63;
  const int cg = t >> 6;
#pragma unroll
  for (int it = 0; it < 16; ++it) {
    const int c = it * 4 + cg;
    const size_t gi = ((size_t)b * C_ + c) * N_ + n0 + j;
    out[gi] = x[gi] * s + msum[j * 65 + c];
  }
}

// Fallback (only if ws too small for xt): direct gather in native layout.
__global__ __launch_bounds__(256) void direct_k(const float* __restrict__ x,
                                                const int* __restrict__ ei,
                                                const float* __restrict__ alpha_p,
                                                float* __restrict__ out) {
  const int bid = blockIdx.x;          // B * N/256 = 128 blocks
  const int b   = bid & 7;
  const int n   = (bid >> 3) * 256 + threadIdx.x;
  int idx[K_];
#pragma unroll
  for (int k = 0; k < K_; ++k) idx[k] = ei[((size_t)b * N_ + n) * K_ + k];
  const float s = 1.0f + alpha_p[0];
  for (int c = 0; c < C_; ++c) {
    const float* xr = &x[((size_t)b * C_ + c) * N_];
    float acc = 0.f;
#pragma unroll
    for (int k = 0; k < K_; ++k) acc += xr[idx[k]];
    out[((size_t)b * C_ + c) * N_ + n] = xr[n] * s + acc;
  }
}

extern "C" void kernel_launch(void* const* d_in, const int* in_sizes, int n_in,
                              void* d_out, int out_size, void* d_ws, size_t ws_size,
                              hipStream_t stream) {
  const float* x     = (const float*)d_in[0];
  const int*   ei    = (const int*)d_in[1];
  const float* alpha = (const float*)d_in[2];
  float*       out   = (float*)d_out;

  const size_t xt_bytes = (size_t)B_ * N_ * C_ * sizeof(float);
  if (ws_size >= xt_bytes) {
    float* xt = (float*)d_ws;
    transpose_k<<<B_ * (N_ / 64), 256, 0, stream>>>(x, xt);
    aggregate_k<<<B_ * (N_ / 64), 256, 0, stream>>>(x, xt, ei, alpha, out);
  } else {
    direct_k<<<B_ * (N_ / 256), 256, 0, stream>>>(x, ei, alpha, out);
  }
}

// Round 2
// 11.882 us; speedup vs baseline: 1.5167x; 1.5167x over previous
//
#include <hip/hip_runtime.h>

#define B_ 8
#define C_ 64
#define N_ 4096
#define K_ 16
#define THREADS 1024
#define NPT (N_ / THREADS)   // 4 nodes per thread

// One block per (batch, channel-pair). The block's 2-channel x-slice
// (4096 nodes x 2 ch x 4B = 32 KB) lives in LDS; all 16 neighbor gathers
// per node are ds_read_b64 from LDS instead of L2. Output fused with
// (1+alpha)*x using registers kept from the staging pass.
__global__ __launch_bounds__(THREADS) void fused_k(const float* __restrict__ x,
                                                   const int* __restrict__ ei,
                                                   const float* __restrict__ alpha_p,
                                                   float* __restrict__ out) {
  __shared__ float2 xs[N_];          // 32 KB
  const int bid = blockIdx.x;        // 256 = 8 batches * 32 channel-pairs
  const int b   = bid & 7;           // batch on low bits -> per-XCD locality for ei[b]
  const int c0  = (bid >> 3) * 2;
  const int t   = threadIdx.x;

  const float* xr0 = &x[((size_t)b * C_ + c0) * N_];
  const float* xr1 = xr0 + N_;

  // Stage: coalesced reads (lane = node), conflict-free b64 LDS writes.
  float v0[NPT], v1[NPT];
#pragma unroll
  for (int i = 0; i < NPT; ++i) {
    const int n = t + i * THREADS;
    v0[i] = xr0[n];
    v1[i] = xr1[n];
    xs[n] = make_float2(v0[i], v1[i]);
  }
  __syncthreads();

  const float s = 1.0f + alpha_p[0];
  const int* eib = &ei[(size_t)b * N_ * K_];
  float* o0 = &out[((size_t)b * C_ + c0) * N_];
  float* o1 = o0 + N_;

#pragma unroll
  for (int i = 0; i < NPT; ++i) {
    const int n = t + i * THREADS;
    // 64 B of edge ids for this node via 4x int4 (L1-resident pattern:
    // consecutive lanes are 64 B apart, 4 loads fully consume each line).
    const int4* ep = reinterpret_cast<const int4*>(&eib[(size_t)n * K_]);
    int idx[K_];
    *reinterpret_cast<int4*>(&idx[0])  = ep[0];
    *reinterpret_cast<int4*>(&idx[4])  = ep[1];
    *reinterpret_cast<int4*>(&idx[8])  = ep[2];
    *reinterpret_cast<int4*>(&idx[12]) = ep[3];

    float ax = 0.f, ay = 0.f;
#pragma unroll
    for (int k = 0; k < K_; ++k) {
      const float2 g = xs[idx[k]];   // ds_read_b64, random bank
      ax += g.x;
      ay += g.y;
    }
    // Coalesced fused write-out (lane = node).
    o0[n] = v0[i] * s + ax;
    o1[n] = v1[i] * s + ay;
  }
}

extern "C" void kernel_launch(void* const* d_in, const int* in_sizes, int n_in,
                              void* d_out, int out_size, void* d_ws, size_t ws_size,
                              hipStream_t stream) {
  const float* x     = (const float*)d_in[0];
  const int*   ei    = (const int*)d_in[1];
  const float* alpha = (const float*)d_in[2];
  float*       out   = (float*)d_out;
  (void)d_ws; (void)ws_size;

  fused_k<<<B_ * (C_ / 2), THREADS, 0, stream>>>(x, ei, alpha, out);
}